// Round 1
// baseline (1843.236 us; speedup 1.0000x reference)
//
#include <hip/hip_runtime.h>
#include <cstdio>
#include <cstdint>

typedef __bf16 bf16x8 __attribute__((ext_vector_type(8)));
typedef float  f32x4  __attribute__((ext_vector_type(4)));

static constexpr float ATT_SCALE = 0.08838834764831845f;  // 1/sqrt(128)

// ---------------------------------------------------------------- helpers
__device__ __forceinline__ void async16(void* lds, const void* g) {
  // generic->AS casts via integer round-trip: AS1 is 64-bit; AS3 pointer is the
  // low 32 bits of the generic LDS address (4GiB-aligned aperture).
  __builtin_amdgcn_global_load_lds(
      (const __attribute__((address_space(1))) void*)(uintptr_t)g,
      (__attribute__((address_space(3))) void*)(uint32_t)(uintptr_t)lds,
      16, 0, 0);
}

// ---------------------------------------------------------------- cast x -> bf16
__global__ __launch_bounds__(256) void k_cast_bf16(const float* __restrict__ x,
                                                   __bf16* __restrict__ y) {
  size_t i = ((size_t)blockIdx.x * 256 + threadIdx.x) * 8;
  float4 a = *(const float4*)(x + i);
  float4 b = *(const float4*)(x + i + 4);
  bf16x8 v;
  v[0] = (__bf16)a.x; v[1] = (__bf16)a.y; v[2] = (__bf16)a.z; v[3] = (__bf16)a.w;
  v[4] = (__bf16)b.x; v[5] = (__bf16)b.y; v[6] = (__bf16)b.z; v[7] = (__bf16)b.w;
  *(bf16x8*)(y + i) = v;
}

// ---------------------------------------------------------------- W[R][C] f32 -> Wt[C][R] bf16
__global__ __launch_bounds__(256) void k_transpose_cast(const float* __restrict__ W,
                                                        __bf16* __restrict__ Wt,
                                                        int R, int C) {
  __shared__ float tile[32][33];
  int c0 = blockIdx.x * 32, r0 = blockIdx.y * 32;
  int tx = threadIdx.x, ty = threadIdx.y;  // 32 x 8
#pragma unroll
  for (int j = 0; j < 4; ++j)
    tile[ty + j * 8][tx] = W[(size_t)(r0 + ty + j * 8) * C + c0 + tx];
  __syncthreads();
#pragma unroll
  for (int j = 0; j < 4; ++j)
    Wt[(size_t)(c0 + ty + j * 8) * R + r0 + tx] = (__bf16)tile[tx][ty + j * 8];
}

// ---------------------------------------------------------------- gemm_bt (m97 structure)
// C[M,N] = A[M,K] @ Bt[N,K]^T + bias.  BM=BN=128, BK=32, 256 thr (2x2 waves of 64x64).
// MODE 0: C bf16 row-major.  MODE 1: C f32 row-major.  MODE 2: C bf16 written as
//         vt[b][n][s] with b=row>>11, s=row&2047 (N must be 128).
template <int MODE>
__global__ __launch_bounds__(256, 2) void k_gemm_bt(const __bf16* __restrict__ A,
                                                    const __bf16* __restrict__ Bt,
                                                    const float* __restrict__ bias,
                                                    void* __restrict__ Cout,
                                                    int M, int N, int K) {
  const int tid = threadIdx.x;
  const int w = tid >> 6, l = tid & 63, l15 = l & 15, lg = l >> 4;
  const int wr = w >> 1, wc = w & 1;
  const int m0 = blockIdx.y * 128, n0 = blockIdx.x * 128;
  __shared__ alignas(16) __bf16 As[128 * 32];
  __shared__ alignas(16) __bf16 Bs[128 * 32];

  const f32x4 z4 = {0.f, 0.f, 0.f, 0.f};
  f32x4 acc[4][4];
#pragma unroll
  for (int a = 0; a < 4; ++a)
#pragma unroll
    for (int b = 0; b < 4; ++b) acc[a][b] = z4;

  float bv4[4];
#pragma unroll
  for (int tc = 0; tc < 4; ++tc) bv4[tc] = bias[n0 + wc * 64 + tc * 16 + l15];

  for (int k0 = 0; k0 < K; k0 += 32) {
    __syncthreads();
#pragma unroll
    for (int i = 0; i < 2; ++i) {
      int idx = i * 256 + tid;
      int r = idx >> 2, c = (idx & 3) * 8;
      async16(As + idx * 8, A + (size_t)(m0 + r) * K + k0 + c);
      async16(Bs + idx * 8, Bt + (size_t)(n0 + r) * K + k0 + c);
    }
    __syncthreads();
    bf16x8 af[4], bf[4];
#pragma unroll
    for (int t = 0; t < 4; ++t)
      af[t] = *(const bf16x8*)(As + (wr * 64 + t * 16 + l15) * 32 + lg * 8);
#pragma unroll
    for (int t = 0; t < 4; ++t)
      bf[t] = *(const bf16x8*)(Bs + (wc * 64 + t * 16 + l15) * 32 + lg * 8);
#pragma unroll
    for (int tr = 0; tr < 4; ++tr)
#pragma unroll
      for (int tc = 0; tc < 4; ++tc)
        acc[tr][tc] = __builtin_amdgcn_mfma_f32_16x16x32_bf16(af[tr], bf[tc],
                                                              acc[tr][tc], 0, 0, 0);
  }

#pragma unroll
  for (int tr = 0; tr < 4; ++tr)
#pragma unroll
    for (int tc = 0; tc < 4; ++tc)
#pragma unroll
      for (int rg = 0; rg < 4; ++rg) {
        int row = m0 + wr * 64 + tr * 16 + lg * 4 + rg;
        int col = n0 + wc * 64 + tc * 16 + l15;
        float v = acc[tr][tc][rg] + bv4[tc];
        if (MODE == 0) {
          ((__bf16*)Cout)[(size_t)row * N + col] = (__bf16)v;
        } else if (MODE == 1) {
          ((float*)Cout)[(size_t)row * N + col] = v;
        } else {
          int bb = row >> 11, s = row & 2047;
          ((__bf16*)Cout)[((size_t)(bb * 128 + col)) * 2048 + s] = (__bf16)v;
        }
      }
}

// ---------------------------------------------------------------- fused MQA attention
// grid (16 qtiles, 16 heads, 4 batch), 256 thr (4 waves, each owns 32 q-rows).
// Per (b,h,qt): pass1 online (m,L) over 64-wide K tiles; pass2 recomputes S,
// writes normalized p to scores, accumulates O = P@V via LDS round-trip for P.
__global__ __launch_bounds__(256, 2) void k_attn(const __bf16* __restrict__ qb,   // [8192][2048]
                                                 const __bf16* __restrict__ kb,   // [8192][128]
                                                 const __bf16* __restrict__ vt,   // [4][128][2048]
                                                 float* __restrict__ scores,      // [4][16][2048][2048]
                                                 __bf16* __restrict__ ab) {       // [8192][2048]
  const int qt = blockIdx.x, h = blockIdx.y, b = blockIdx.z;
  const int tid = threadIdx.x, w = tid >> 6, l = tid & 63, l15 = l & 15, lg = l >> 4;
  __shared__ alignas(16) __bf16 ldsK[64 * 128];   // [kpos][hd], xor-swizzled 16B chunks
  __shared__ alignas(16) __bf16 ldsV[128 * 64];   // [hd][kpos], xor-swizzled
  __shared__ alignas(16) __bf16 ldsP[128 * 64];   // [qrow][kpos], xor-swizzled

  // Q fragments (A-layout): row = w*32+tr*16+l15, k = ks*32+lg*8; 64B-coalesced.
  bf16x8 qf[2][4];
  {
    const __bf16* qbase = qb + (size_t)(b * 2048 + qt * 128 + w * 32 + l15) * 2048 +
                          h * 128 + lg * 8;
#pragma unroll
    for (int tr = 0; tr < 2; ++tr)
#pragma unroll
      for (int ks = 0; ks < 4; ++ks)
        qf[tr][ks] = *(const bf16x8*)(qbase + tr * 16 * 2048 + ks * 32);
  }
  const __bf16* kbase = kb + (size_t)b * 2048 * 128;
  const __bf16* vbase = vt + (size_t)b * 128 * 2048;

  auto stageK = [&](int kt) {
#pragma unroll
    for (int i = 0; i < 4; ++i) {
      int idx = i * 256 + tid;        // 0..1023 ; 16 chunks of 16B per 128-elem row
      int r = idx >> 4, j = idx & 15;
      bf16x8 d = *(const bf16x8*)(kbase + (size_t)(kt * 64 + r) * 128 + j * 8);
      *(bf16x8*)(ldsK + r * 128 + (j ^ (r & 7)) * 8) = d;
    }
  };
  auto stageV = [&](int kt) {
#pragma unroll
    for (int i = 0; i < 4; ++i) {
      int idx = i * 256 + tid;        // 8 chunks per 64-elem row
      int r = idx >> 3, j = idx & 7;
      bf16x8 d = *(const bf16x8*)(vbase + (size_t)r * 2048 + kt * 64 + j * 8);
      *(bf16x8*)(ldsV + r * 64 + (j ^ (r & 7)) * 8) = d;
    }
  };
  auto computeS = [&](f32x4(&sacc)[2][4]) {
    const f32x4 z4 = {0.f, 0.f, 0.f, 0.f};
#pragma unroll
    for (int tr = 0; tr < 2; ++tr)
#pragma unroll
      for (int tc = 0; tc < 4; ++tc) sacc[tr][tc] = z4;
#pragma unroll
    for (int ks = 0; ks < 4; ++ks) {
      bf16x8 kf[4];
#pragma unroll
      for (int tc = 0; tc < 4; ++tc) {
        int r = tc * 16 + l15;
        kf[tc] = *(const bf16x8*)(ldsK + r * 128 + ((ks * 4 + lg) ^ (r & 7)) * 8);
      }
#pragma unroll
      for (int tr = 0; tr < 2; ++tr)
#pragma unroll
        for (int tc = 0; tc < 4; ++tc)
          sacc[tr][tc] = __builtin_amdgcn_mfma_f32_16x16x32_bf16(qf[tr][ks], kf[tc],
                                                                 sacc[tr][tc], 0, 0, 0);
    }
  };

  float mrow[8], lrow[8];
#pragma unroll
  for (int i = 0; i < 8; ++i) { mrow[i] = -3.0e38f; lrow[i] = 0.f; }

  // ---- pass 1: online row max / sum-exp
  for (int kt = 0; kt < 32; ++kt) {
    __syncthreads();
    stageK(kt);
    __syncthreads();
    f32x4 sacc[2][4];
    computeS(sacc);
#pragma unroll
    for (int tr = 0; tr < 2; ++tr)
#pragma unroll
      for (int rg = 0; rg < 4; ++rg) {
        int idx = tr * 4 + rg;
        float mx = fmaxf(fmaxf(sacc[tr][0][rg], sacc[tr][1][rg]),
                         fmaxf(sacc[tr][2][rg], sacc[tr][3][rg])) * ATT_SCALE;
#pragma unroll
        for (int d = 1; d < 16; d <<= 1) mx = fmaxf(mx, __shfl_xor(mx, d));
        float mnew = fmaxf(mrow[idx], mx);
        float s = 0.f;
#pragma unroll
        for (int tc = 0; tc < 4; ++tc)
          s += __expf(sacc[tr][tc][rg] * ATT_SCALE - mnew);
#pragma unroll
        for (int d = 1; d < 16; d <<= 1) s += __shfl_xor(s, d);
        lrow[idx] = lrow[idx] * __expf(mrow[idx] - mnew) + s;
        mrow[idx] = mnew;
      }
  }

  float rl[8];
#pragma unroll
  for (int i = 0; i < 8; ++i) rl[i] = 1.0f / lrow[i];

  const f32x4 z4 = {0.f, 0.f, 0.f, 0.f};
  f32x4 oacc[2][8];
#pragma unroll
  for (int tr = 0; tr < 2; ++tr)
#pragma unroll
    for (int tv = 0; tv < 8; ++tv) oacc[tr][tv] = z4;

  float* scb = scores + ((size_t)((b * 16 + h) * 2048 + qt * 128)) * 2048;

  // ---- pass 2: recompute S, write scores, accumulate O
  for (int kt = 0; kt < 32; ++kt) {
    __syncthreads();
    stageK(kt);
    stageV(kt);
    __syncthreads();
    f32x4 sacc[2][4];
    computeS(sacc);
#pragma unroll
    for (int tr = 0; tr < 2; ++tr)
#pragma unroll
      for (int rg = 0; rg < 4; ++rg) {
        int idx = tr * 4 + rg;
        int rloc = w * 32 + tr * 16 + lg * 4 + rg;
#pragma unroll
        for (int tc = 0; tc < 4; ++tc) {
          float p = __expf(sacc[tr][tc][rg] * ATT_SCALE - mrow[idx]) * rl[idx];
          scb[(size_t)rloc * 2048 + kt * 64 + tc * 16 + l15] = p;
          int col = tc * 16 + l15;
          int j = col >> 3;
          ldsP[rloc * 64 + ((j ^ (rloc & 7)) * 8) + (col & 7)] = (__bf16)p;
        }
      }
    // PV: each wave reads only its own 32 P rows -> no barrier needed (in-wave
    // lgkmcnt ordering covers the write->read dependency).
#pragma unroll
    for (int ks2 = 0; ks2 < 2; ++ks2) {
      bf16x8 pf[2];
#pragma unroll
      for (int tr = 0; tr < 2; ++tr) {
        int r = w * 32 + tr * 16 + l15;
        pf[tr] = *(const bf16x8*)(ldsP + r * 64 + (((ks2 * 4 + lg) ^ (r & 7))) * 8);
      }
#pragma unroll
      for (int tv = 0; tv < 8; ++tv) {
        int r2 = tv * 16 + l15;
        bf16x8 vf = *(const bf16x8*)(ldsV + r2 * 64 + (((ks2 * 4 + lg) ^ (r2 & 7))) * 8);
#pragma unroll
        for (int tr = 0; tr < 2; ++tr)
          oacc[tr][tv] = __builtin_amdgcn_mfma_f32_16x16x32_bf16(pf[tr], vf,
                                                                 oacc[tr][tv], 0, 0, 0);
      }
    }
  }

  // epilogue: ab[token][h*128+hd]
#pragma unroll
  for (int tr = 0; tr < 2; ++tr)
#pragma unroll
    for (int tv = 0; tv < 8; ++tv)
#pragma unroll
      for (int rg = 0; rg < 4; ++rg) {
        int rloc = w * 32 + tr * 16 + lg * 4 + rg;
        size_t tok = (size_t)(b * 2048 + qt * 128 + rloc);
        ab[tok * 2048 + h * 128 + tv * 16 + l15] = (__bf16)oacc[tr][tv][rg];
      }
}

// ---------------------------------------------------------------- launch
extern "C" void kernel_launch(void* const* d_in, const int* in_sizes, int n_in,
                              void* d_out, int out_size, void* d_ws, size_t ws_size,
                              hipStream_t stream) {
  const float* x  = (const float*)d_in[0];
  const float* Wq = (const float*)d_in[1];
  const float* bq = (const float*)d_in[2];
  const float* Wk = (const float*)d_in[3];
  const float* bk = (const float*)d_in[4];
  const float* Wv = (const float*)d_in[5];
  const float* bv = (const float*)d_in[6];
  const float* Wo = (const float*)d_in[7];
  const float* bo = (const float*)d_in[8];

  char* ws = (char*)d_ws;
  size_t off = 0;
  auto alloc = [&](size_t bytes) { void* p = ws + off; off += bytes; return p; };
  __bf16* xb   = (__bf16*)alloc(33554432);  // x bf16        [8192][2048]
  __bf16* Wqt  = (__bf16*)alloc(8388608);   // Wq^T bf16     [2048][2048]
  __bf16* Wkt  = (__bf16*)alloc(524288);    // Wk^T bf16     [128][2048]
  __bf16* Wvt  = (__bf16*)alloc(524288);    // Wv^T bf16     [128][2048]
  __bf16* Wot  = (__bf16*)alloc(8388608);   // Wo^T bf16     [2048][2048]
  __bf16* qbuf = (__bf16*)alloc(33554432);  // q bf16        [8192][2048]
  __bf16* kbuf = (__bf16*)alloc(2097152);   // k bf16        [8192][128]
  __bf16* vtb  = (__bf16*)alloc(2097152);   // v^T bf16      [4][128][2048]
  __bf16* abuf = (__bf16*)alloc(33554432);  // attn out bf16 [8192][2048]
  if (off > ws_size) {
    fprintf(stderr, "kernel_launch: ws too small: need %zu, have %zu\n", off, ws_size);
    return;
  }

  float* out    = (float*)d_out;
  float* scores = out + (size_t)4 * 2048 * 2048;  // out first, then scores

  k_cast_bf16<<<8192, 256, 0, stream>>>(x, xb);
  k_transpose_cast<<<dim3(64, 64), dim3(32, 8), 0, stream>>>(Wq, Wqt, 2048, 2048);
  k_transpose_cast<<<dim3(4, 64),  dim3(32, 8), 0, stream>>>(Wk, Wkt, 2048, 128);
  k_transpose_cast<<<dim3(4, 64),  dim3(32, 8), 0, stream>>>(Wv, Wvt, 2048, 128);
  k_transpose_cast<<<dim3(64, 64), dim3(32, 8), 0, stream>>>(Wo, Wot, 2048, 2048);

  k_gemm_bt<0><<<dim3(16, 64), 256, 0, stream>>>(xb, Wqt, bq, qbuf, 8192, 2048, 2048);
  k_gemm_bt<0><<<dim3(1, 64),  256, 0, stream>>>(xb, Wkt, bk, kbuf, 8192, 128, 2048);
  k_gemm_bt<2><<<dim3(1, 64),  256, 0, stream>>>(xb, Wvt, bv, vtb,  8192, 128, 2048);

  k_attn<<<dim3(16, 16, 4), 256, 0, stream>>>(qbuf, kbuf, vtb, scores, abuf);

  k_gemm_bt<1><<<dim3(16, 64), 256, 0, stream>>>(abuf, Wot, bo, out, 8192, 2048, 2048);
}